// Round 1
// 176.233 us; speedup vs baseline: 1.1804x; 1.1804x over previous
//
#include <hip/hip_runtime.h>
#include <math.h>

#define DIM 4096

typedef _Float16 v8h __attribute__((ext_vector_type(8)));
typedef float v4f __attribute__((ext_vector_type(4)));

// CNOT ladder dest->src map pi(d) = (d ^ (d>>1)) ^ ((d&1)*0xC00); pinv = its inverse.
// pinv is GF(2)-LINEAR: pinv(a^b) = pinv(a)^pinv(b)  (gray-decode and the
// parity-driven 0xC00 correction are both linear).
__device__ __forceinline__ int pinv(int s) {
  int p = __popc(s) & 1;
  int d = s ^ (p ? 0xC00 : 0);
  d ^= d >> 1; d ^= d >> 2; d ^= d >> 4; d ^= d >> 8;
  return d & 4095;
}
constexpr int pinv_c(int s) {
  int p = __builtin_popcount(s) & 1;
  int d = s ^ (p ? 0xC00 : 0);
  d ^= d >> 1; d ^= d >> 2; d ^= d >> 4; d ^= d >> 8;
  return d & 4095;
}

// Bank swizzle: XOR byte-addr bits [5:4] (16B quads within a 64B row) with
// row[2:1]^row[6:5]. Reads vary m in row[3:0]; writes vary m in row[7:4]; both
// get spread across bank-quads. Quad-granular -> b128/b64 stay aligned.
__device__ __forceinline__ int swz4(int row) {
  return (((row >> 1) ^ (row >> 5)) & 3) << 4;
}

// L0 byte address (comp 0) of amplitude d.  L0 layout: row = G2*16+G1
// (G0=d[11:8], G1=d[7:4], G2=d[3:0]); row content: [16 f16 re | 16 f16 im],
// re f16 k at byte 2k, im at 32+2k, then quad-swizzled.  XOR-linear in d.
constexpr int l0d(int d) {
  int row = (d & 15) * 16 + ((d >> 4) & 15);
  int f2 = ((row >> 1) ^ (row >> 5)) & 3;
  return (row << 6) ^ ((((d >> 8) & 15)) << 1) ^ (f2 << 4);
}

// pass-2 fold write deltas for C-row index r (G0-delta r<<8 through pinv+l0d)
constexpr int DR1 = l0d(pinv_c(1 << 8));
constexpr int DR2 = l0d(pinv_c(2 << 8));
constexpr int DR3 = l0d(pinv_c(3 << 8));

// ---- One pass: state(A) x gate(B) MFMA.  State is A: lane(m,q) supplies
// A[m][k=q*8+j] = [Sr|Si] stacked (q<2 -> re rows k, q>=2 -> im rows k-16).
// Gate is B: lane(m,q) supplies B[k=q*8+j][m] -- exactly the existing
// make_gates2 packing (unchanged).  C: col=lane&15 = i (new group value),
// row=q*4+r = tile-column (old next-group value).
// Layouts: L0 (pass-0 src): row=G2*16+G1, planes-in-row, k=G0.
//          L1 (pass-1 src): row=G0*16+G2, content [q][re r0..3|im r0..3], k=G1.
//          L2 (pass-2 src): row=G1*16+G0, same content form, k=G2.
// Pass p reads rows t4*16+m of src, writes rows m*16+t4 of dst (transpose-on-
// write into the next pass's layout) -> reads b128/b64, writes b128.
// Pass 2 applies the CNOT fold on its write (pinv scatter, 8x b16).
template <int PASS>
__device__ __forceinline__ void do_pass(const char* src, char* dst,
                                        const v8h* __restrict__ Af, int mat, int t) {
  const int lane = t & 63, wv = t >> 6;
  const int m = lane & 15, q = lane >> 4, qb = q & 1, pm = q >> 1;
  const v8h b_re = Af[(mat * 2 + 0) * 64 + lane];
  const v8h b_im = Af[(mat * 2 + 1) * 64 + lane];
  int abase = 0;
  if constexpr (PASS == 2) {
    // s_base = (q*4)<<8 | (wv*4)<<4 | m  (r and tt folded in via linearity)
    abase = l0d(pinv((q << 10) | (wv << 6) | m));
  }
#pragma unroll
  for (int tt = 0; tt < 4; ++tt) {
    const int t4 = wv * 4 + tt;
    const int row = t4 * 16 + m;
    const int sz = swz4(row);
    v8h a;
    if constexpr (PASS == 0) {
      // planes-in-row: one b128 = 8 f16 of comp pm, k = qb*8 + j
      a = *(const v8h*)(src + (((row << 6) + pm * 32 + qb * 16) ^ sz));
    } else {
      // [q][comp][r] rows: two b64 at k-quads 2qb, 2qb+1, comp pm
      const int ad = ((row << 6) + qb * 32 + pm * 8) ^ sz;
      const uint2 lo = *(const uint2*)(src + ad);
      const uint2 hi = *(const uint2*)(src + (ad ^ 16));
      a = __builtin_bit_cast(v8h, make_uint4(lo.x, lo.y, hi.x, hi.y));
    }
    const v4f cre = __builtin_amdgcn_mfma_f32_16x16x32_f16(a, b_re, (v4f){0.f, 0.f, 0.f, 0.f}, 0, 0, 0);
    const v4f cim = __builtin_amdgcn_mfma_f32_16x16x32_f16(a, b_im, (v4f){0.f, 0.f, 0.f, 0.f}, 0, 0, 0);
    if constexpr (PASS < 2) {
      // write row = i*16 + t4, k = q*4+r: [re r0..3 | im r0..3] = one b128
      const int wrow = m * 16 + t4;
      v8h w;
#pragma unroll
      for (int r = 0; r < 4; ++r) {
        w[r] = (_Float16)cre[r];
        w[4 + r] = (_Float16)cim[r];
      }
      *(v8h*)(dst + (((wrow << 6) + q * 16) ^ swz4(wrow))) = w;
    } else {
      // fold: d = pinv(s), s = (q*4+r)<<8 | t4<<4 | m.  XOR-linear -> base ^ const.
      const int ab = abase ^ l0d(pinv_c(tt << 4));
      *(_Float16*)(dst + ab) = (_Float16)cre[0];
      *(_Float16*)(dst + (ab ^ DR1)) = (_Float16)cre[1];
      *(_Float16*)(dst + (ab ^ DR2)) = (_Float16)cre[2];
      *(_Float16*)(dst + (ab ^ DR3)) = (_Float16)cre[3];
      *(_Float16*)(dst + (ab ^ 32)) = (_Float16)cim[0];
      *(_Float16*)(dst + (ab ^ (DR1 ^ 32))) = (_Float16)cim[1];
      *(_Float16*)(dst + (ab ^ (DR2 ^ 32))) = (_Float16)cim[2];
      *(_Float16*)(dst + (ab ^ (DR3 ^ 32))) = (_Float16)cim[3];
    }
  }
}

// Fuse RZ*RY*RX per (layer,qubit), build 12 per-pass 16x16 complex kron
// matrices in per-lane fragment order (UNCHANGED from verified kernel; the
// same per-lane data now serves as the MFMA B operand).
__global__ void make_gates2(const float* __restrict__ ax, const float* __restrict__ ay,
                            const float* __restrict__ az, _Float16* __restrict__ Aw) {
  __shared__ float g4[48][4];  // ar, ai, br, bi per (layer,qubit)
  const int id = threadIdx.x;
  if (id < 48) {
    float th = 0.5f * ax[id], ph = 0.5f * ay[id], lm = 0.5f * az[id];
    float c = cosf(th), s = sinf(th);
    float cy = cosf(ph), sy = sinf(ph);
    float cl = cosf(lm), sl = sinf(lm);
    float m00r = cy * c, m00i = sy * s;
    float m01r = -sy * c, m01i = -cy * s;
    g4[id][0] = cl * m00r + sl * m00i;
    g4[id][1] = cl * m00i - sl * m00r;
    g4[id][2] = cl * m01r + sl * m01i;
    g4[id][3] = cl * m01i - sl * m01r;
  }
  __syncthreads();
  const int mat = id >> 6, lane = id & 63;
  const int m = lane & 15, q = lane >> 4;
  const int layer = mat / 3, pass = mat % 3, qbase = pass * 4;
#pragma unroll
  for (int j = 0; j < 8; ++j) {
    const int k = q * 8 + j, kk = k & 15;
    float cr = 1.f, ci = 0.f;
#pragma unroll
    for (int bp = 3; bp >= 0; --bp) {
      const int qq = qbase + (3 - bp);
      const int ib = (m >> bp) & 1, kb = (kk >> bp) & 1;
      const float* gg = g4[layer * 12 + qq];
      float er, ei;
      if (ib == 0 && kb == 0) { er = gg[0]; ei = gg[1]; }
      else if (ib == 0 && kb == 1) { er = gg[2]; ei = gg[3]; }
      else if (ib == 1 && kb == 0) { er = -gg[2]; ei = gg[3]; }
      else { er = gg[0]; ei = -gg[1]; }
      const float nr = cr * er - ci * ei, ni = cr * ei + ci * er;
      cr = nr; ci = ni;
    }
    const float reval = (k < 16) ? cr : -ci;  // [Mr | -Mi]
    const float imval = (k < 16) ? ci : cr;   // [Mi |  Mr]
    Aw[((mat * 2 + 0) * 64 + lane) * 8 + j] = (_Float16)reval;
    Aw[((mat * 2 + 1) * 64 + lane) * 8 + j] = (_Float16)imval;
  }
}

// One block per batch element; fp16 state in two ping-pong 16KB LDS buffers.
// State pre-scaled x64 (fp16 inputs ~N(0,1)); rounding points identical to the
// previous fp32-store/cvt-on-read kernel.
__global__ __launch_bounds__(256, 4) void qsim3(const float* __restrict__ x,
                                                const v8h* __restrict__ Af,
                                                float* __restrict__ out) {
  __shared__ __align__(16) char buf[2][16384];
  const int t = threadIdx.x;
  const int b = blockIdx.x;
  const float* xb = x + (size_t)b * DIM;

  // ---- load |x|, block-reduce sum & sum-of-squares ----
  float w[16];
  float sw = 0.f, sw2 = 0.f;
#pragma unroll
  for (int j = 0; j < 16; ++j) {
    float a = fabsf(xb[t + (j << 8)]);
    w[j] = a; sw += a; sw2 += a * a;
  }
#pragma unroll
  for (int off = 32; off; off >>= 1) {
    sw += __shfl_down(sw, off, 64);
    sw2 += __shfl_down(sw2, off, 64);
  }
  float* red = (float*)buf[1];  // buf[1] dead until pass 0 writes it
  if ((t & 63) == 0) { red[t >> 6] = sw; red[4 + (t >> 6)] = sw2; }
  __syncthreads();
  sw = (red[0] + red[1]) + (red[2] + red[3]);
  sw2 = (red[4] + red[5]) + (red[6] + red[7]);

  // ---- amplitude encoding (faithful branches), x64 prescale ----
  float sc = 0.f;
  const bool ok = (sw > 1e-8f);
  if (ok) {
    float wnscale = rsqrtf(fmaxf(sw, 1e-8f));
    float norm = sqrtf(sw2 / sw);
    sc = ((norm > 1e-8f) ? (wnscale / fmaxf(norm, 1e-8f)) : wnscale) * 64.0f;
  }
  // write L0 into buf[0]: amp a=(j<<8)|t -> row = (t&15)*16 + (t>>4), k=j
  {
    const int row = ((t & 15) << 4) | (t >> 4);
    const int rb = (row << 6) ^ swz4(row);
    v8h h0, h1, z;
#pragma unroll
    for (int j = 0; j < 8; ++j) {
      h0[j] = (_Float16)(ok ? w[j] * sc : 1.0f);
      h1[j] = (_Float16)(ok ? w[8 + j] * sc : 1.0f);
      z[j] = (_Float16)0.f;
    }
    *(v8h*)(buf[0] + (rb ^ 0)) = h0;   // re k 0..7
    *(v8h*)(buf[0] + (rb ^ 16)) = h1;  // re k 8..15
    *(v8h*)(buf[0] + (rb ^ 32)) = z;   // im k 0..7
    *(v8h*)(buf[0] + (rb ^ 48)) = z;   // im k 8..15
  }
  __syncthreads();

  char* s = buf[0];
  char* d = buf[1];
#pragma unroll 1
  for (int l = 0; l < 4; ++l) {
    do_pass<0>(s, d, Af, l * 3 + 0, t);  // qubits 0-3  (bits 11-8)
    __syncthreads();
    do_pass<1>(d, s, Af, l * 3 + 1, t);  // qubits 4-7  (bits 7-4)
    __syncthreads();
    do_pass<2>(s, d, Af, l * 3 + 2, t);  // qubits 8-11 (bits 3-0) + CNOT fold
    __syncthreads();
    char* tmp = s; s = d; d = tmp;       // next layer reads what pass-2 wrote
  }

  // ---- output |amp| / 64 (state back in s = buf[0], L0 layout) ----
  float* ob = out + (size_t)b * DIM;
  {
    const int row = ((t & 15) << 4) | (t >> 4);
    const int rb = (row << 6) ^ swz4(row);
    const v8h r0 = *(const v8h*)(s + (rb ^ 0));
    const v8h r1 = *(const v8h*)(s + (rb ^ 16));
    const v8h i0 = *(const v8h*)(s + (rb ^ 32));
    const v8h i1 = *(const v8h*)(s + (rb ^ 48));
#pragma unroll
    for (int j = 0; j < 8; ++j) {
      float re = (float)r0[j], im = (float)i0[j];
      ob[(j << 8) | t] = sqrtf(re * re + im * im) * 0.015625f;
      float re2 = (float)r1[j], im2 = (float)i1[j];
      ob[((j + 8) << 8) | t] = sqrtf(re2 * re2 + im2 * im2) * 0.015625f;
    }
  }
}

extern "C" void kernel_launch(void* const* d_in, const int* in_sizes, int n_in,
                              void* d_out, int out_size, void* d_ws, size_t ws_size,
                              hipStream_t stream) {
  const float* x = (const float*)d_in[0];
  const float* ax = (const float*)d_in[1];
  const float* ay = (const float*)d_in[2];
  const float* az = (const float*)d_in[3];
  _Float16* Aw = (_Float16*)d_ws;  // 12 mats * 2 comps * 64 lanes * 8 halves = 24576 B
  make_gates2<<<1, 768, 0, stream>>>(ax, ay, az, Aw);
  qsim3<<<4096, 256, 0, stream>>>(x, (const v8h*)Aw, (float*)d_out);
}

// Round 3
// 159.043 us; speedup vs baseline: 1.3080x; 1.1081x over previous
//
#include <hip/hip_runtime.h>
#include <math.h>

#define DIM 4096

typedef _Float16 v8h __attribute__((ext_vector_type(8)));
typedef _Float16 v4h __attribute__((ext_vector_type(4)));
typedef float v4f __attribute__((ext_vector_type(4)));
typedef unsigned int v2u __attribute__((ext_vector_type(2)));

// ---- Swizzled LDS byte address for (row, off); 256 rows x 64B per buffer.
// quad bits [5:4] ^= row[2:1]^row[6:5]  (spreads m across quads)
// half bit  [6]   ^= row[4]             (spreads m across bank halves when the
//                                        row's low bit is wave-constant)
// XOR-linear, bijective, quad-granular -> b64/b128 stay aligned.
__device__ __forceinline__ int adr(int row, int off) {
  return ((row << 6) | off) ^ ((((row >> 1) ^ (row >> 5)) & 3) << 4)
                            ^ (((row >> 4) & 1) << 6);
}

// Layouts (content of a 64B row, fp16):
//  L0 (pass-0 src): row = G2*16+G1, [re: f16 G0=p at byte 2p | im at 32+2p]
//  L1 (pass-1 src): row = G0*16+G2, quad kq holds k=G1 in {4kq..4kq+3}: [re r0-3 | im r0-3]
//  L2 (pass-2 src): row = G1*16+G0, same quad form, k = G2
// CNOT ladder pi(d) = d ^ (d>>1) ^ ((d&1)*0xC00) (dest->src) is GF(2)-linear;
// pass 2 writes UNfolded (contiguous); the fold is applied on the NEXT pass-0
// read (and epilogue): state[d] = val[pi(d)].
//   pi(k<<8 | m<<4 | t4):  G0' = gray4(k) ^ 12*(t4&1)
//                          G1' = gray4(m) ^ ((k&1)<<3)   <- row bit 3 (low nibble!)
//                          G2' = (t4^(t4>>1)) ^ ((m&1)<<3)
// -> even k in row r0, odd k in r0^8, all 8 positions inside ONE 16B quad.

template <int PASS, bool FOLD>
__device__ __forceinline__ void do_pass(const char* __restrict__ src, char* __restrict__ dst,
                                        const v8h* __restrict__ Af, int mat, int t) {
  const int lane = t & 63, wv = t >> 6;
  const int m = lane & 15, q = lane >> 4;
  const int qb = q & 1, pm = q >> 1;
  const v8h b_re = Af[(mat * 2 + 0) * 64 + lane];
  const v8h b_im = Af[(mat * 2 + 1) * 64 + lane];
  const int gm = (m ^ (m >> 1)) & 15;  // gray4(m)
#pragma unroll
  for (int tt = 0; tt < 4; ++tt) {
    const int t4 = wv * 4 + tt;
    v8h a;
    if constexpr (PASS == 0 && FOLD) {
      // folded read: state[(k, G1=m, G2=t4)] = val[pi(...)]
      const int t4g = t4 ^ (t4 >> 1);
      const bool qs = ((qb ^ tt) & 1) != 0;      // octet select = qb ^ (t4&1)
      const int off = pm * 32 + (qs ? 16 : 0);
      const int r0 = ((t4g ^ ((m & 1) << 3)) << 4) | gm;
      const uint4 E = *(const uint4*)(src + adr(r0, off));      // even k
      const uint4 O = *(const uint4*)(src + adr(r0 ^ 8, off));  // odd k
      // dword pairing: case qs=0 -> slots use d(0,1,3,2); qs=1 -> d(2,3,1,0)
      const unsigned e0 = qs ? E.z : E.x, e1 = qs ? E.w : E.y;
      const unsigned e2 = qs ? E.y : E.w, e3 = qs ? E.x : E.z;
      const unsigned o0 = qs ? O.z : O.x, o1 = qs ? O.w : O.y;
      const unsigned o2 = qs ? O.y : O.w, o3 = qs ? O.x : O.z;
      uint4 av;
      av.x = __builtin_amdgcn_perm(o0, e0, 0x07060100u);  // [E lo16 | O hi16]
      av.y = __builtin_amdgcn_perm(o1, e1, 0x05040302u);  // [E hi16 | O lo16]
      av.z = __builtin_amdgcn_perm(o2, e2, 0x07060100u);
      av.w = __builtin_amdgcn_perm(o3, e3, 0x05040302u);
      a = __builtin_bit_cast(v8h, av);
    } else if constexpr (PASS == 0) {
      a = *(const v8h*)(src + adr(t4 * 16 + m, pm * 32 + qb * 16));
    } else {
      // one b128 = [re r0-3 | im r0-3] of k-quad (2qb+pm); exchange halves with
      // lane^32 (pm partner): ret.x = [x_lo|y_lo], ret.y = [x_hi|y_hi]
      const uint4 r = *(const uint4*)(src + adr(t4 * 16 + m, (2 * qb + pm) * 16));
      const v2u s0 = __builtin_amdgcn_permlane32_swap(r.x, r.z, false, false);
      const v2u s1 = __builtin_amdgcn_permlane32_swap(r.y, r.w, false, false);
      uint4 av;
      av.x = s0.x; av.y = s1.x; av.z = s0.y; av.w = s1.y;
      a = __builtin_bit_cast(v8h, av);
    }
    const v4f cre = __builtin_amdgcn_mfma_f32_16x16x32_f16(a, b_re, (v4f){0.f, 0.f, 0.f, 0.f}, 0, 0, 0);
    const v4f cim = __builtin_amdgcn_mfma_f32_16x16x32_f16(a, b_im, (v4f){0.f, 0.f, 0.f, 0.f}, 0, 0, 0);
    // C: col = lane&15 (new group value), row = q*4+r (transpose-on-write)
    const int wrow = m * 16 + t4;
    if constexpr (PASS < 2) {
      v8h w;
#pragma unroll
      for (int r2 = 0; r2 < 4; ++r2) {
        w[r2] = (_Float16)cre[r2];
        w[4 + r2] = (_Float16)cim[r2];
      }
      *(v8h*)(dst + adr(wrow, q * 16)) = w;
    } else {
      // L0 plain content: re k=q*4+r at byte q*8+2r, im at +32 (two b64)
      v4h wre, wim;
#pragma unroll
      for (int r2 = 0; r2 < 4; ++r2) {
        wre[r2] = (_Float16)cre[r2];
        wim[r2] = (_Float16)cim[r2];
      }
      *(v4h*)(dst + adr(wrow, q * 8)) = wre;
      *(v4h*)(dst + adr(wrow, 32 + q * 8)) = wim;
    }
  }
}

// Fuse RZ*RY*RX per (layer,qubit), build 12 per-pass 16x16 complex kron
// matrices in per-lane B-fragment order (unchanged, verified).
__global__ void make_gates2(const float* __restrict__ ax, const float* __restrict__ ay,
                            const float* __restrict__ az, _Float16* __restrict__ Aw) {
  __shared__ float g4[48][4];
  const int id = threadIdx.x;
  if (id < 48) {
    float th = 0.5f * ax[id], ph = 0.5f * ay[id], lm = 0.5f * az[id];
    float c = cosf(th), s = sinf(th);
    float cy = cosf(ph), sy = sinf(ph);
    float cl = cosf(lm), sl = sinf(lm);
    float m00r = cy * c, m00i = sy * s;
    float m01r = -sy * c, m01i = -cy * s;
    g4[id][0] = cl * m00r + sl * m00i;
    g4[id][1] = cl * m00i - sl * m00r;
    g4[id][2] = cl * m01r + sl * m01i;
    g4[id][3] = cl * m01i - sl * m01r;
  }
  __syncthreads();
  const int mat = id >> 6, lane = id & 63;
  const int m = lane & 15, q = lane >> 4;
  const int layer = mat / 3, pass = mat % 3, qbase = pass * 4;
#pragma unroll
  for (int j = 0; j < 8; ++j) {
    const int k = q * 8 + j, kk = k & 15;
    float cr = 1.f, ci = 0.f;
#pragma unroll
    for (int bp = 3; bp >= 0; --bp) {
      const int qq = qbase + (3 - bp);
      const int ib = (m >> bp) & 1, kb = (kk >> bp) & 1;
      const float* gg = g4[layer * 12 + qq];
      float er, ei;
      if (ib == 0 && kb == 0) { er = gg[0]; ei = gg[1]; }
      else if (ib == 0 && kb == 1) { er = gg[2]; ei = gg[3]; }
      else if (ib == 1 && kb == 0) { er = -gg[2]; ei = gg[3]; }
      else { er = gg[0]; ei = -gg[1]; }
      const float nr = cr * er - ci * ei, ni = cr * ei + ci * er;
      cr = nr; ci = ni;
    }
    const float reval = (k < 16) ? cr : -ci;  // [Mr | -Mi]
    const float imval = (k < 16) ? ci : cr;   // [Mi |  Mr]
    Aw[((mat * 2 + 0) * 64 + lane) * 8 + j] = (_Float16)reval;
    Aw[((mat * 2 + 1) * 64 + lane) * 8 + j] = (_Float16)imval;
  }
}

__global__ __launch_bounds__(256, 4) void qsim4(const float* __restrict__ x,
                                                const v8h* __restrict__ Af,
                                                float* __restrict__ out) {
  __shared__ __align__(16) char buf[2][16384];
  const int t = threadIdx.x;
  const int b = blockIdx.x;
  const float* xb = x + (size_t)b * DIM;

  // ---- load |x|, block-reduce sum & sum-of-squares ----
  float w[16];
  float sw = 0.f, sw2 = 0.f;
#pragma unroll
  for (int j = 0; j < 16; ++j) {
    float aa = fabsf(xb[t + (j << 8)]);
    w[j] = aa; sw += aa; sw2 += aa * aa;
  }
#pragma unroll
  for (int off = 32; off; off >>= 1) {
    sw += __shfl_down(sw, off, 64);
    sw2 += __shfl_down(sw2, off, 64);
  }
  float* red = (float*)buf[1];  // buf[1] is dead until pass 0 writes it
  if ((t & 63) == 0) { red[t >> 6] = sw; red[4 + (t >> 6)] = sw2; }
  __syncthreads();
  sw = (red[0] + red[1]) + (red[2] + red[3]);
  sw2 = (red[4] + red[5]) + (red[6] + red[7]);

  // ---- amplitude encoding (faithful branches), x64 prescale ----
  float sc = 0.f;
  const bool ok = (sw > 1e-8f);
  if (ok) {
    float wnscale = rsqrtf(fmaxf(sw, 1e-8f));
    float norm = sqrtf(sw2 / sw);
    sc = ((norm > 1e-8f) ? (wnscale / fmaxf(norm, 1e-8f)) : wnscale) * 64.0f;
  }
  // write plain L0: amp (j<<8)|t -> row = (t&15)*16 + (t>>4), re byte 2j
  {
    const int row = ((t & 15) << 4) | (t >> 4);
    v8h h0, h1, z;
#pragma unroll
    for (int j = 0; j < 8; ++j) {
      h0[j] = (_Float16)(ok ? w[j] * sc : 1.0f);
      h1[j] = (_Float16)(ok ? w[8 + j] * sc : 1.0f);
      z[j] = (_Float16)0.f;
    }
    *(v8h*)(buf[0] + adr(row, 0)) = h0;
    *(v8h*)(buf[0] + adr(row, 16)) = h1;
    *(v8h*)(buf[0] + adr(row, 32)) = z;
    *(v8h*)(buf[0] + adr(row, 48)) = z;
  }
  __syncthreads();

  char* s = buf[0];
  char* d = buf[1];
  // layer 0: encode wrote identity layout -> unfolded pass 0
  do_pass<0, false>(s, d, Af, 0, t); __syncthreads();
  do_pass<1, false>(d, s, Af, 1, t); __syncthreads();
  do_pass<2, false>(s, d, Af, 2, t); __syncthreads();
  { char* tmp = s; s = d; d = tmp; }
#pragma unroll 1
  for (int l = 1; l < 4; ++l) {
    do_pass<0, true>(s, d, Af, l * 3 + 0, t); __syncthreads();
    do_pass<1, false>(d, s, Af, l * 3 + 1, t); __syncthreads();
    do_pass<2, false>(s, d, Af, l * 3 + 2, t); __syncthreads();
    char* tmp = s; s = d; d = tmp;
  }

  // ---- epilogue: state[d] = val[pi(d)]; out = |state|/64, coalesced ----
  // thread t, amps d=(j<<8)|t: even j in row re_row, odd j in re_row^8
  // (G1' bit 3 = row bit 3 -- low nibble), f16 position gray4(j) ^ 12*(t&1);
  // per-lane b64 addressing absorbs quad/pair variance -> compile-time indices.
  float* ob = out + (size_t)b * DIM;
  {
    const int g = t ^ (t >> 1);
    const int re_row = (g & 15) * 16 + ((g >> 4) & 15);
    const int ro = re_row ^ 8;   // odd-j rows: G1' ^= 8 (row low nibble)
    const int offA = (t & 1) ? 24 : 0;
    const int offB = (t & 1) ? 16 : 8;
    const v4h E0 = *(const v4h*)(s + adr(re_row, offA));
    const v4h E1 = *(const v4h*)(s + adr(re_row, offB));
    const v4h E2 = *(const v4h*)(s + adr(re_row, offA ^ 24));
    const v4h E3 = *(const v4h*)(s + adr(re_row, offB ^ 24));
    const v4h O0 = *(const v4h*)(s + adr(ro, offA));
    const v4h O1 = *(const v4h*)(s + adr(ro, offB));
    const v4h O2 = *(const v4h*)(s + adr(ro, offA ^ 24));
    const v4h O3 = *(const v4h*)(s + adr(ro, offB ^ 24));
    const v4h IE0 = *(const v4h*)(s + adr(re_row, 32 + offA));
    const v4h IE1 = *(const v4h*)(s + adr(re_row, 32 + offB));
    const v4h IE2 = *(const v4h*)(s + adr(re_row, 32 + (offA ^ 24)));
    const v4h IE3 = *(const v4h*)(s + adr(re_row, 32 + (offB ^ 24)));
    const v4h IO0 = *(const v4h*)(s + adr(ro, 32 + offA));
    const v4h IO1 = *(const v4h*)(s + adr(ro, 32 + offB));
    const v4h IO2 = *(const v4h*)(s + adr(ro, 32 + (offA ^ 24)));
    const v4h IO3 = *(const v4h*)(s + adr(ro, 32 + (offB ^ 24)));
#define MAG(J, VR, VI, IDX)                                           \
  {                                                                   \
    const float re_ = (float)VR[IDX], im_ = (float)VI[IDX];           \
    ob[((J) << 8) | t] = sqrtf(re_ * re_ + im_ * im_) * 0.015625f;    \
  }
    MAG(0, E0, IE0, 0)  MAG(2, E0, IE0, 3)  MAG(4, E1, IE1, 2)  MAG(6, E1, IE1, 1)
    MAG(8, E2, IE2, 0)  MAG(10, E2, IE2, 3) MAG(12, E3, IE3, 2) MAG(14, E3, IE3, 1)
    MAG(1, O0, IO0, 1)  MAG(3, O0, IO0, 2)  MAG(5, O1, IO1, 3)  MAG(7, O1, IO1, 0)
    MAG(9, O2, IO2, 1)  MAG(11, O2, IO2, 2) MAG(13, O3, IO3, 3) MAG(15, O3, IO3, 0)
#undef MAG
  }
}

extern "C" void kernel_launch(void* const* d_in, const int* in_sizes, int n_in,
                              void* d_out, int out_size, void* d_ws, size_t ws_size,
                              hipStream_t stream) {
  const float* x = (const float*)d_in[0];
  const float* ax = (const float*)d_in[1];
  const float* ay = (const float*)d_in[2];
  const float* az = (const float*)d_in[3];
  _Float16* Aw = (_Float16*)d_ws;  // 12 mats * 2 comps * 64 lanes * 8 halves = 24576 B
  make_gates2<<<1, 768, 0, stream>>>(ax, ay, az, Aw);
  qsim4<<<4096, 256, 0, stream>>>(x, (const v8h*)Aw, (float*)d_out);
}

// Round 4
// 154.926 us; speedup vs baseline: 1.3428x; 1.0266x over previous
//
#include <hip/hip_runtime.h>
#include <math.h>

#define DIM 4096

typedef _Float16 v8h __attribute__((ext_vector_type(8)));
typedef float v4f __attribute__((ext_vector_type(4)));
typedef unsigned int v2u __attribute__((ext_vector_type(2)));

// pack two f32 -> one dword of two f16 (RTZ) in a single VALU instr
__device__ __forceinline__ unsigned pkrtz(float a, float b) {
  return __builtin_bit_cast(unsigned, __builtin_amdgcn_cvt_pkrtz(a, b));
}

// ---- Swizzled LDS byte address for (row, off); 256 rows x 64B per buffer.
// quad bits [5:4] ^= row[2:1]^row[6:5]; half bit [6] ^= row[4].
// XOR-linear, bijective, quad-granular -> b64/b128 stay aligned.
__device__ __forceinline__ int adr(int row, int off) {
  return ((row << 6) | off) ^ ((((row >> 1) ^ (row >> 5)) & 3) << 4)
                            ^ (((row >> 4) & 1) << 6);
}

// Layouts (content of a 64B row, fp16):
//  L0i (pass-0 src, layers 0-2 out of pass-2): row = G2*16+G1,
//      dword p = [re of G0=p | im of G0=p]  (interleaved complex)
//  L0  (epilogue src, layer-3 pass-2 out): row = G2*16+G1, re f16 at byte 2p, im at 32+2p
//  L1 (pass-1 src): row = G0*16+G2, quad kq: [re r0-3 | im r0-3], k=G1=4kq+r
//  L2 (pass-2 src): row = G1*16+G0, same quad form, k = G2
// CNOT ladder pi(d) = d ^ (d>>1) ^ ((d&1)*0xC00) (dest->src), GF(2)-linear;
// pass 2 writes UNfolded; fold applied on next pass-0 read / epilogue:
//   pi(p<<8 | m<<4 | t4):  G0' = gray4(p) ^ 12*(t4&1)   (dword position)
//                          G1' = gray4(m) ^ ((p&1)<<3)  (row low nibble: bit3)
//                          G2' = gray4(t4) ^ ((m&1)<<3)
// With L0i, the [re|im] pair of one amplitude is ONE dword -> fold read =
// 2 b128 (even-p row r0, odd-p row r0^8) + 8 cndmask, zero v_perm. The
// per-(q,dd) dword index works out to: dw = {E[0^2q0], O[1^2q0], E[3^2q0],
// O[2^2q0]}, q0 = q&1 (gray-code algebra, hand-checked 4 cases).

template <int PASS, bool FOLD, bool LAST>
__device__ __forceinline__ void do_pass(const char* __restrict__ src, char* __restrict__ dst,
                                        const v8h* __restrict__ Af, int mat, int t) {
  const int lane = t & 63, wv = t >> 6;
  const int m = lane & 15, q = lane >> 4;
  const int qb = q & 1, pm = q >> 1;
  const v8h b_re = Af[(mat * 2 + 0) * 64 + lane];
  const v8h b_im = Af[(mat * 2 + 1) * 64 + lane];
  const int gm = (m ^ (m >> 1)) & 15;  // gray4(m)
  const bool qh = (q & 1) != 0;
#pragma unroll
  for (int tt = 0; tt < 4; ++tt) {
    const int t4 = wv * 4 + tt;
    v8h a;
    if constexpr (PASS == 0 && FOLD) {
      // folded read from L0i: lane needs dwords [re|im] of p = 4q+dd,
      // at amplitude pi(p<<8|m<<4|t4).
      const int t4g = t4 ^ (t4 >> 1);
      const int gq2 = ((q ^ (q >> 1)) & 3) ^ ((tt & 1) ? 3 : 0);  // quad = gray2(q)^3*(t4&1)
      const int r0 = ((t4g ^ ((m & 1) << 3)) << 4) | gm;
      const uint4 E = *(const uint4*)(src + adr(r0, gq2 * 16));      // even p
      const uint4 O = *(const uint4*)(src + adr(r0 ^ 8, gq2 * 16));  // odd p
      uint4 av;
      av.x = qh ? E.z : E.x;
      av.y = qh ? O.w : O.y;
      av.z = qh ? E.y : E.w;
      av.w = qh ? O.x : O.z;
      a = __builtin_bit_cast(v8h, av);
    } else if constexpr (PASS == 0) {
      // L0i plain: quad q holds p = 4q..4q+3 interleaved [re|im] dwords
      a = *(const v8h*)(src + adr(t4 * 16 + m, q * 16));
    } else {
      // one b128 = [re r0-3 | im r0-3] of k-quad (2qb+pm); exchange halves with
      // lane^32 (pm partner): ret.x = [x_lo|y_lo], ret.y = [x_hi|y_hi]
      const uint4 r = *(const uint4*)(src + adr(t4 * 16 + m, (2 * qb + pm) * 16));
      const v2u s0 = __builtin_amdgcn_permlane32_swap(r.x, r.z, false, false);
      const v2u s1 = __builtin_amdgcn_permlane32_swap(r.y, r.w, false, false);
      uint4 av;
      av.x = s0.x; av.y = s1.x; av.z = s0.y; av.w = s1.y;
      a = __builtin_bit_cast(v8h, av);
    }
    const v4f cre = __builtin_amdgcn_mfma_f32_16x16x32_f16(a, b_re, (v4f){0.f, 0.f, 0.f, 0.f}, 0, 0, 0);
    const v4f cim = __builtin_amdgcn_mfma_f32_16x16x32_f16(a, b_im, (v4f){0.f, 0.f, 0.f, 0.f}, 0, 0, 0);
    // C: col = lane&15 (new group value), row = q*4+r (transpose-on-write)
    const int wrow = m * 16 + t4;
    if constexpr (PASS < 2) {
      uint4 w;
      w.x = pkrtz(cre[0], cre[1]);
      w.y = pkrtz(cre[2], cre[3]);
      w.z = pkrtz(cim[0], cim[1]);
      w.w = pkrtz(cim[2], cim[3]);
      *(uint4*)(dst + adr(wrow, q * 16)) = w;
    } else if constexpr (!LAST) {
      // L0i out: dword r = [re|im] of G0 = q*4+r -> one b128 at quad q
      uint4 w;
      w.x = pkrtz(cre[0], cim[0]);
      w.y = pkrtz(cre[1], cim[1]);
      w.z = pkrtz(cre[2], cim[2]);
      w.w = pkrtz(cre[3], cim[3]);
      *(uint4*)(dst + adr(wrow, q * 16)) = w;
    } else {
      // L0 (separated) out for the epilogue: re k=q*4+r at byte q*8+2r, im +32
      uint2 wr, wi;
      wr.x = pkrtz(cre[0], cre[1]);
      wr.y = pkrtz(cre[2], cre[3]);
      wi.x = pkrtz(cim[0], cim[1]);
      wi.y = pkrtz(cim[2], cim[3]);
      *(uint2*)(dst + adr(wrow, q * 8)) = wr;
      *(uint2*)(dst + adr(wrow, 32 + q * 8)) = wi;
    }
  }
}

// Fuse RZ*RY*RX per (layer,qubit), build 12 per-pass 16x16 complex kron
// matrices in per-lane B-fragment order. Pass-0 mats use the L0i k-labeling
// (k'=q*8+j -> element p = 4q+(j>>1), type = j&1: re/im interleaved); pass-1/2
// mats keep the stacked labeling (k<16 -> re p=k, k>=16 -> im p=k-16).
__global__ void make_gates2(const float* __restrict__ ax, const float* __restrict__ ay,
                            const float* __restrict__ az, _Float16* __restrict__ Aw) {
  __shared__ float g4[48][4];
  const int id = threadIdx.x;
  if (id < 48) {
    float th = 0.5f * ax[id], ph = 0.5f * ay[id], lm = 0.5f * az[id];
    float c = cosf(th), s = sinf(th);
    float cy = cosf(ph), sy = sinf(ph);
    float cl = cosf(lm), sl = sinf(lm);
    float m00r = cy * c, m00i = sy * s;
    float m01r = -sy * c, m01i = -cy * s;
    g4[id][0] = cl * m00r + sl * m00i;
    g4[id][1] = cl * m00i - sl * m00r;
    g4[id][2] = cl * m01r + sl * m01i;
    g4[id][3] = cl * m01i - sl * m01r;
  }
  __syncthreads();
  const int mat = id >> 6, lane = id & 63;
  const int m = lane & 15, q = lane >> 4;
  const int layer = mat / 3, pass = mat % 3, qbase = pass * 4;
#pragma unroll
  for (int j = 0; j < 8; ++j) {
    int p, ty;
    if (pass == 0) { p = q * 4 + (j >> 1); ty = j & 1; }
    else { p = (q * 8 + j) & 15; ty = (q >= 2) ? 1 : 0; }
    float cr = 1.f, ci = 0.f;
#pragma unroll
    for (int bp = 3; bp >= 0; --bp) {
      const int qq = qbase + (3 - bp);
      const int ib = (m >> bp) & 1, kb = (p >> bp) & 1;
      const float* gg = g4[layer * 12 + qq];
      float er, ei;
      if (ib == 0 && kb == 0) { er = gg[0]; ei = gg[1]; }
      else if (ib == 0 && kb == 1) { er = gg[2]; ei = gg[3]; }
      else if (ib == 1 && kb == 0) { er = -gg[2]; ei = gg[3]; }
      else { er = gg[0]; ei = -gg[1]; }
      const float nr = cr * er - ci * ei, ni = cr * ei + ci * er;
      cr = nr; ci = ni;
    }
    const float reval = ty ? -ci : cr;  // re-comp fragment
    const float imval = ty ? cr : ci;   // im-comp fragment
    Aw[((mat * 2 + 0) * 64 + lane) * 8 + j] = (_Float16)reval;
    Aw[((mat * 2 + 1) * 64 + lane) * 8 + j] = (_Float16)imval;
  }
}

__global__ __launch_bounds__(256, 4) void qsim5(const float* __restrict__ x,
                                                const v8h* __restrict__ Af,
                                                float* __restrict__ out) {
  __shared__ __align__(16) char buf[2][16384];
  const int t = threadIdx.x;
  const int b = blockIdx.x;
  const float* xb = x + (size_t)b * DIM;

  // ---- load |x|, block-reduce sum & sum-of-squares ----
  float wa[16];
  float sw = 0.f, sw2 = 0.f;
#pragma unroll
  for (int j = 0; j < 16; ++j) {
    float aa = fabsf(xb[t + (j << 8)]);
    wa[j] = aa; sw += aa; sw2 += aa * aa;
  }
#pragma unroll
  for (int off = 32; off; off >>= 1) {
    sw += __shfl_down(sw, off, 64);
    sw2 += __shfl_down(sw2, off, 64);
  }
  float* red = (float*)buf[1];  // buf[1] is dead until pass 0 writes it
  if ((t & 63) == 0) { red[t >> 6] = sw; red[4 + (t >> 6)] = sw2; }
  __syncthreads();
  sw = (red[0] + red[1]) + (red[2] + red[3]);
  sw2 = (red[4] + red[5]) + (red[6] + red[7]);

  // ---- amplitude encoding (faithful branches), x64 prescale ----
  float sc = 0.f;
  const bool ok = (sw > 1e-8f);
  if (ok) {
    float wnscale = rsqrtf(fmaxf(sw, 1e-8f));
    float norm = sqrtf(sw2 / sw);
    sc = ((norm > 1e-8f) ? (wnscale / fmaxf(norm, 1e-8f)) : wnscale) * 64.0f;
  }
  const float off0 = ok ? 0.f : 1.f;  // !ok: amp = 1/64 * 64 = 1.0
  // write L0i: amp (j<<8)|t -> row = (t&15)*16 + (t>>4), dword j = [re|0]
  {
    const int row = ((t & 15) << 4) | (t >> 4);
#pragma unroll
    for (int Q = 0; Q < 4; ++Q) {
      uint4 w;
      w.x = pkrtz(fmaf(wa[Q * 4 + 0], sc, off0), 0.f);
      w.y = pkrtz(fmaf(wa[Q * 4 + 1], sc, off0), 0.f);
      w.z = pkrtz(fmaf(wa[Q * 4 + 2], sc, off0), 0.f);
      w.w = pkrtz(fmaf(wa[Q * 4 + 3], sc, off0), 0.f);
      *(uint4*)(buf[0] + adr(row, Q * 16)) = w;
    }
  }
  __syncthreads();

  char* s = buf[0];
  char* d = buf[1];
  // layer 0: encode wrote identity (unfolded) L0i
  do_pass<0, false, false>(s, d, Af, 0, t); __syncthreads();
  do_pass<1, false, false>(d, s, Af, 1, t); __syncthreads();
  do_pass<2, false, false>(s, d, Af, 2, t); __syncthreads();
  { char* tmp = s; s = d; d = tmp; }
#pragma unroll 1
  for (int l = 1; l < 3; ++l) {
    do_pass<0, true, false>(s, d, Af, l * 3 + 0, t); __syncthreads();
    do_pass<1, false, false>(d, s, Af, l * 3 + 1, t); __syncthreads();
    do_pass<2, false, false>(s, d, Af, l * 3 + 2, t); __syncthreads();
    char* tmp = s; s = d; d = tmp;
  }
  // layer 3: pass-2 writes separated L0 for the epilogue
  do_pass<0, true, false>(s, d, Af, 9, t); __syncthreads();
  do_pass<1, false, false>(d, s, Af, 10, t); __syncthreads();
  do_pass<2, false, true>(s, d, Af, 11, t); __syncthreads();
  { char* tmp = s; s = d; d = tmp; }

  // ---- epilogue: state[d] = val[pi(d)]; out = |state|/64, coalesced ----
  // (unchanged, verified R3) even j in row re_row, odd j in re_row^8,
  // f16 position gray4(j) ^ 12*(t&1); per-lane b64 addressing absorbs
  // quad/pair variance -> compile-time extraction indices.
  typedef _Float16 v4h __attribute__((ext_vector_type(4)));
  float* ob = out + (size_t)b * DIM;
  {
    const int g = t ^ (t >> 1);
    const int re_row = (g & 15) * 16 + ((g >> 4) & 15);
    const int ro = re_row ^ 8;
    const int offA = (t & 1) ? 24 : 0;
    const int offB = (t & 1) ? 16 : 8;
    const v4h E0 = *(const v4h*)(s + adr(re_row, offA));
    const v4h E1 = *(const v4h*)(s + adr(re_row, offB));
    const v4h E2 = *(const v4h*)(s + adr(re_row, offA ^ 24));
    const v4h E3 = *(const v4h*)(s + adr(re_row, offB ^ 24));
    const v4h O0 = *(const v4h*)(s + adr(ro, offA));
    const v4h O1 = *(const v4h*)(s + adr(ro, offB));
    const v4h O2 = *(const v4h*)(s + adr(ro, offA ^ 24));
    const v4h O3 = *(const v4h*)(s + adr(ro, offB ^ 24));
    const v4h IE0 = *(const v4h*)(s + adr(re_row, 32 + offA));
    const v4h IE1 = *(const v4h*)(s + adr(re_row, 32 + offB));
    const v4h IE2 = *(const v4h*)(s + adr(re_row, 32 + (offA ^ 24)));
    const v4h IE3 = *(const v4h*)(s + adr(re_row, 32 + (offB ^ 24)));
    const v4h IO0 = *(const v4h*)(s + adr(ro, 32 + offA));
    const v4h IO1 = *(const v4h*)(s + adr(ro, 32 + offB));
    const v4h IO2 = *(const v4h*)(s + adr(ro, 32 + (offA ^ 24)));
    const v4h IO3 = *(const v4h*)(s + adr(ro, 32 + (offB ^ 24)));
#define MAG(J, VR, VI, IDX)                                                       \
  {                                                                               \
    const float re_ = (float)VR[IDX], im_ = (float)VI[IDX];                       \
    ob[((J) << 8) | t] = __builtin_amdgcn_sqrtf(re_ * re_ + im_ * im_) * 0.015625f; \
  }
    MAG(0, E0, IE0, 0)  MAG(2, E0, IE0, 3)  MAG(4, E1, IE1, 2)  MAG(6, E1, IE1, 1)
    MAG(8, E2, IE2, 0)  MAG(10, E2, IE2, 3) MAG(12, E3, IE3, 2) MAG(14, E3, IE3, 1)
    MAG(1, O0, IO0, 1)  MAG(3, O0, IO0, 2)  MAG(5, O1, IO1, 3)  MAG(7, O1, IO1, 0)
    MAG(9, O2, IO2, 1)  MAG(11, O2, IO2, 2) MAG(13, O3, IO3, 3) MAG(15, O3, IO3, 0)
#undef MAG
  }
}

extern "C" void kernel_launch(void* const* d_in, const int* in_sizes, int n_in,
                              void* d_out, int out_size, void* d_ws, size_t ws_size,
                              hipStream_t stream) {
  const float* x = (const float*)d_in[0];
  const float* ax = (const float*)d_in[1];
  const float* ay = (const float*)d_in[2];
  const float* az = (const float*)d_in[3];
  _Float16* Aw = (_Float16*)d_ws;  // 12 mats * 2 comps * 64 lanes * 8 halves = 24576 B
  make_gates2<<<1, 768, 0, stream>>>(ax, ay, az, Aw);
  qsim5<<<4096, 256, 0, stream>>>(x, (const v8h*)Aw, (float*)d_out);
}

// Round 5
// 149.092 us; speedup vs baseline: 1.3953x; 1.0391x over previous
//
#include <hip/hip_runtime.h>
#include <math.h>

#define DIM 4096

typedef _Float16 v8h __attribute__((ext_vector_type(8)));
typedef float v4f __attribute__((ext_vector_type(4)));
typedef unsigned int v2u __attribute__((ext_vector_type(2)));

// pack two f32 -> one dword of two f16 (RTZ) in a single VALU instr
__device__ __forceinline__ unsigned pkrtz(float a, float b) {
  return __builtin_bit_cast(unsigned, __builtin_amdgcn_cvt_pkrtz(a, b));
}

// ---- Swizzled LDS byte address for (row, off); 256 rows x 64B per buffer.
// quad bits [5:4] ^= row[2:1]^row[6:5]; half bit [6] ^= row[4].
// XOR-linear, bijective, quad-granular -> b64/b128 stay aligned.
__device__ __forceinline__ int adr(int row, int off) {
  return ((row << 6) | off) ^ ((((row >> 1) ^ (row >> 5)) & 3) << 4)
                            ^ (((row >> 4) & 1) << 6);
}

// Layouts (content of a 64B row, fp16):
//  L0i (pass-0 src): row = G2*16+G1, dword p = [re G0=p | im G0=p]
//  L0  (epilogue src, layer-3 pass-2 out): row = G2*16+G1, re at 2p, im at 32+2p
//  L2 (pass-2 src): row = G1*16+G0, quad kq: [re r0-3 | im r0-3], k = G2 = 4kq+r
// CNOT ladder pi(d) = d ^ (d>>1) ^ ((d&1)*0xC00) (dest->src), GF(2)-linear;
// pass 2 writes UNfolded; fold applied on next pass-0 read / epilogue:
//   pi(p<<8 | m<<4 | t4):  G0' = gray4(p) ^ 12*(t4&1)   (dword position)
//                          G1' = gray4(m) ^ ((p&1)<<3)  (row low nibble: bit3)
//                          G2' = gray4(t4) ^ ((m&1)<<3)
//
// FUSED pass0+pass1 (in-register, no LDS between):
// After pass-0 MFMA, lane(n=G0'=lane&15, q) holds (G1 = q*4+r, G2 = tile) for
// both components. Pass-1 A-fragment wants lane(m'=G0', q') to hold 8 f16 of
// k' = q'*8+j (stacked re G1 0-15 | im G1 0-15): a pure exchange across lane
// bits [5:4]. With R0=pk(re(4q),re(4q+1)), R1=pk(re(4q+2),re(4q+3)), I0,I1 im:
//   (P0,Q0)=pl32swap(R0,I0); (P1,Q1)=pl32swap(R1,I1)
//   (dw0,dw2)=pl16swap(P0,Q0); (dw1,dw3)=pl16swap(P1,Q1)
// gives the A fragment directly (row-by-row verified against the pl32
// semantics pinned by the working pass-2 code: first = [a_lo|b_lo] positional,
// 16-swap analogous within 32-halves). 8 VALU, zero DS, zero barriers.

template <bool FOLD>
__device__ __forceinline__ void pass01(const char* __restrict__ src, char* __restrict__ dst,
                                       const v8h* __restrict__ Af, int mat, int t) {
  const int lane = t & 63, wv = t >> 6;
  const int m = lane & 15, q = lane >> 4;
  const bool qh = (q & 1) != 0;
  const v8h b0_re = Af[((mat) * 2 + 0) * 64 + lane];
  const v8h b0_im = Af[((mat) * 2 + 1) * 64 + lane];
  const v8h b1_re = Af[((mat + 1) * 2 + 0) * 64 + lane];
  const v8h b1_im = Af[((mat + 1) * 2 + 1) * 64 + lane];
  const int gm = (m ^ (m >> 1)) & 15;  // gray4(m)
  v4f ar[4], ai[4];
#pragma unroll
  for (int tt = 0; tt < 4; ++tt) {
    const int t4 = wv * 4 + tt;
    v8h a0;
    if constexpr (FOLD) {
      // folded read from L0i (verified R4): even p row r0, odd p row r0^8
      const int t4g = t4 ^ (t4 >> 1);
      const int gq2 = ((q ^ (q >> 1)) & 3) ^ ((tt & 1) ? 3 : 0);
      const int r0 = ((t4g ^ ((m & 1) << 3)) << 4) | gm;
      const uint4 E = *(const uint4*)(src + adr(r0, gq2 * 16));
      const uint4 O = *(const uint4*)(src + adr(r0 ^ 8, gq2 * 16));
      uint4 av;
      av.x = qh ? E.z : E.x;
      av.y = qh ? O.w : O.y;
      av.z = qh ? E.y : E.w;
      av.w = qh ? O.x : O.z;
      a0 = __builtin_bit_cast(v8h, av);
    } else {
      // L0i plain: quad q holds p = 4q..4q+3 interleaved [re|im] dwords
      a0 = *(const v8h*)(src + adr(t4 * 16 + m, q * 16));
    }
    const v4f cre = __builtin_amdgcn_mfma_f32_16x16x32_f16(a0, b0_re, (v4f){0.f, 0.f, 0.f, 0.f}, 0, 0, 0);
    const v4f cim = __builtin_amdgcn_mfma_f32_16x16x32_f16(a0, b0_im, (v4f){0.f, 0.f, 0.f, 0.f}, 0, 0, 0);
    // ---- in-register exchange: pass-0 C layout -> pass-1 A fragment ----
    const unsigned R0 = pkrtz(cre[0], cre[1]);
    const unsigned R1 = pkrtz(cre[2], cre[3]);
    const unsigned I0 = pkrtz(cim[0], cim[1]);
    const unsigned I1 = pkrtz(cim[2], cim[3]);
    const v2u PQ0 = __builtin_amdgcn_permlane32_swap(R0, I0, false, false);
    const v2u PQ1 = __builtin_amdgcn_permlane32_swap(R1, I1, false, false);
    const v2u W02 = __builtin_amdgcn_permlane16_swap(PQ0.x, PQ0.y, false, false);
    const v2u W13 = __builtin_amdgcn_permlane16_swap(PQ1.x, PQ1.y, false, false);
    uint4 a1u;
    a1u.x = W02.x; a1u.y = W13.x; a1u.z = W02.y; a1u.w = W13.y;
    const v8h a1 = __builtin_bit_cast(v8h, a1u);
    ar[tt] = __builtin_amdgcn_mfma_f32_16x16x32_f16(a1, b1_re, (v4f){0.f, 0.f, 0.f, 0.f}, 0, 0, 0);
    ai[tt] = __builtin_amdgcn_mfma_f32_16x16x32_f16(a1, b1_im, (v4f){0.f, 0.f, 0.f, 0.f}, 0, 0, 0);
  }
  // ---- write L2: value (G1'=lane&15, G0'=q*4+r, G2=wv*4+tt) ----
  // row = G1'*16 + G0', quad wv: [re(G2 pairs) | im(G2 pairs)] = one b128.
  // Content bit-identical to the old pass-1 writer; (half,quad) slots get
  // exactly 8 lanes each (conflict-free b128 floor).
  const int colbase = m * 16 + q * 4;
#pragma unroll
  for (int r2 = 0; r2 < 4; ++r2) {
    uint4 w;
    w.x = pkrtz(ar[0][r2], ar[1][r2]);
    w.y = pkrtz(ar[2][r2], ar[3][r2]);
    w.z = pkrtz(ai[0][r2], ai[1][r2]);
    w.w = pkrtz(ai[2][r2], ai[3][r2]);
    *(uint4*)(dst + adr(colbase + r2, wv * 16)) = w;
  }
}

template <bool LAST>
__device__ __forceinline__ void pass2f(const char* __restrict__ src, char* __restrict__ dst,
                                       const v8h* __restrict__ Af, int mat, int t) {
  const int lane = t & 63, wv = t >> 6;
  const int m = lane & 15, q = lane >> 4;
  const int qb = q & 1, pm = q >> 1;
  const v8h b_re = Af[(mat * 2 + 0) * 64 + lane];
  const v8h b_im = Af[(mat * 2 + 1) * 64 + lane];
#pragma unroll
  for (int tt = 0; tt < 4; ++tt) {
    const int t4 = wv * 4 + tt;
    // one b128 = [re r0-3 | im r0-3] of k-quad (2qb+pm); exchange halves with
    // lane^32 partner (verified R3/R4)
    const uint4 r = *(const uint4*)(src + adr(t4 * 16 + m, (2 * qb + pm) * 16));
    const v2u s0 = __builtin_amdgcn_permlane32_swap(r.x, r.z, false, false);
    const v2u s1 = __builtin_amdgcn_permlane32_swap(r.y, r.w, false, false);
    uint4 av;
    av.x = s0.x; av.y = s1.x; av.z = s0.y; av.w = s1.y;
    const v8h a = __builtin_bit_cast(v8h, av);
    const v4f cre = __builtin_amdgcn_mfma_f32_16x16x32_f16(a, b_re, (v4f){0.f, 0.f, 0.f, 0.f}, 0, 0, 0);
    const v4f cim = __builtin_amdgcn_mfma_f32_16x16x32_f16(a, b_im, (v4f){0.f, 0.f, 0.f, 0.f}, 0, 0, 0);
    const int wrow = m * 16 + t4;  // = G2'*16 + G1'
    if constexpr (!LAST) {
      // L0i out: dword r = [re|im] of G0 = q*4+r -> one b128 at quad q
      uint4 w;
      w.x = pkrtz(cre[0], cim[0]);
      w.y = pkrtz(cre[1], cim[1]);
      w.z = pkrtz(cre[2], cim[2]);
      w.w = pkrtz(cre[3], cim[3]);
      *(uint4*)(dst + adr(wrow, q * 16)) = w;
    } else {
      // L0 (separated) out for the epilogue: re k=q*4+r at byte q*8+2r, im +32
      uint2 wr, wi;
      wr.x = pkrtz(cre[0], cre[1]);
      wr.y = pkrtz(cre[2], cre[3]);
      wi.x = pkrtz(cim[0], cim[1]);
      wi.y = pkrtz(cim[2], cim[3]);
      *(uint2*)(dst + adr(wrow, q * 8)) = wr;
      *(uint2*)(dst + adr(wrow, 32 + q * 8)) = wi;
    }
  }
}

// Fuse RZ*RY*RX per (layer,qubit), build 12 per-pass 16x16 complex kron
// matrices in per-lane B-fragment order (unchanged, verified). Pass-0 mats use
// L0i k-labeling (p = 4q+(j>>1), ty = j&1); pass-1/2 stacked labeling.
__global__ void make_gates2(const float* __restrict__ ax, const float* __restrict__ ay,
                            const float* __restrict__ az, _Float16* __restrict__ Aw) {
  __shared__ float g4[48][4];
  const int id = threadIdx.x;
  if (id < 48) {
    float th = 0.5f * ax[id], ph = 0.5f * ay[id], lm = 0.5f * az[id];
    float c = cosf(th), s = sinf(th);
    float cy = cosf(ph), sy = sinf(ph);
    float cl = cosf(lm), sl = sinf(lm);
    float m00r = cy * c, m00i = sy * s;
    float m01r = -sy * c, m01i = -cy * s;
    g4[id][0] = cl * m00r + sl * m00i;
    g4[id][1] = cl * m00i - sl * m00r;
    g4[id][2] = cl * m01r + sl * m01i;
    g4[id][3] = cl * m01i - sl * m01r;
  }
  __syncthreads();
  const int mat = id >> 6, lane = id & 63;
  const int m = lane & 15, q = lane >> 4;
  const int layer = mat / 3, pass = mat % 3, qbase = pass * 4;
#pragma unroll
  for (int j = 0; j < 8; ++j) {
    int p, ty;
    if (pass == 0) { p = q * 4 + (j >> 1); ty = j & 1; }
    else { p = (q * 8 + j) & 15; ty = (q >= 2) ? 1 : 0; }
    float cr = 1.f, ci = 0.f;
#pragma unroll
    for (int bp = 3; bp >= 0; --bp) {
      const int qq = qbase + (3 - bp);
      const int ib = (m >> bp) & 1, kb = (p >> bp) & 1;
      const float* gg = g4[layer * 12 + qq];
      float er, ei;
      if (ib == 0 && kb == 0) { er = gg[0]; ei = gg[1]; }
      else if (ib == 0 && kb == 1) { er = gg[2]; ei = gg[3]; }
      else if (ib == 1 && kb == 0) { er = -gg[2]; ei = gg[3]; }
      else { er = gg[0]; ei = -gg[1]; }
      const float nr = cr * er - ci * ei, ni = cr * ei + ci * er;
      cr = nr; ci = ni;
    }
    const float reval = ty ? -ci : cr;  // re-comp fragment
    const float imval = ty ? cr : ci;   // im-comp fragment
    Aw[((mat * 2 + 0) * 64 + lane) * 8 + j] = (_Float16)reval;
    Aw[((mat * 2 + 1) * 64 + lane) * 8 + j] = (_Float16)imval;
  }
}

__global__ __launch_bounds__(256, 4) void qsim6(const float* __restrict__ x,
                                                const v8h* __restrict__ Af,
                                                float* __restrict__ out) {
  __shared__ __align__(16) char buf[2][16384];
  const int t = threadIdx.x;
  const int b = blockIdx.x;
  const float* xb = x + (size_t)b * DIM;

  // ---- load |x|, block-reduce sum & sum-of-squares ----
  float wa[16];
  float sw = 0.f, sw2 = 0.f;
#pragma unroll
  for (int j = 0; j < 16; ++j) {
    float aa = fabsf(xb[t + (j << 8)]);
    wa[j] = aa; sw += aa; sw2 += aa * aa;
  }
#pragma unroll
  for (int off = 32; off; off >>= 1) {
    sw += __shfl_down(sw, off, 64);
    sw2 += __shfl_down(sw2, off, 64);
  }
  float* red = (float*)buf[1];  // buf[1] is dead until pass01 writes it
  if ((t & 63) == 0) { red[t >> 6] = sw; red[4 + (t >> 6)] = sw2; }
  __syncthreads();
  sw = (red[0] + red[1]) + (red[2] + red[3]);
  sw2 = (red[4] + red[5]) + (red[6] + red[7]);

  // ---- amplitude encoding (faithful branches), x64 prescale ----
  float sc = 0.f;
  const bool ok = (sw > 1e-8f);
  if (ok) {
    float wnscale = rsqrtf(fmaxf(sw, 1e-8f));
    float norm = sqrtf(sw2 / sw);
    sc = ((norm > 1e-8f) ? (wnscale / fmaxf(norm, 1e-8f)) : wnscale) * 64.0f;
  }
  const float off0 = ok ? 0.f : 1.f;  // !ok: amp = 1/64 * 64 = 1.0
  // write L0i into s=buf[0]: amp (j<<8)|t -> row = (t&15)*16 + (t>>4), dw j = [re|0]
  {
    const int row = ((t & 15) << 4) | (t >> 4);
#pragma unroll
    for (int Q = 0; Q < 4; ++Q) {
      uint4 w;
      w.x = pkrtz(fmaf(wa[Q * 4 + 0], sc, off0), 0.f);
      w.y = pkrtz(fmaf(wa[Q * 4 + 1], sc, off0), 0.f);
      w.z = pkrtz(fmaf(wa[Q * 4 + 2], sc, off0), 0.f);
      w.w = pkrtz(fmaf(wa[Q * 4 + 3], sc, off0), 0.f);
      *(uint4*)(buf[0] + adr(row, Q * 16)) = w;
    }
  }
  __syncthreads();

  // Fixed buffer roles: s = buf[0] (L0-side), d = buf[1] (L2-side).
  char* s = buf[0];
  char* d = buf[1];
  // layer 0 (encode wrote identity L0i)
  pass01<false>(s, d, Af, 0, t); __syncthreads();
  pass2f<false>(d, s, Af, 2, t); __syncthreads();
#pragma unroll 1
  for (int l = 1; l < 3; ++l) {
    pass01<true>(s, d, Af, l * 3, t); __syncthreads();
    pass2f<false>(d, s, Af, l * 3 + 2, t); __syncthreads();
  }
  // layer 3: pass-2 writes separated L0 for the epilogue
  pass01<true>(s, d, Af, 9, t); __syncthreads();
  pass2f<true>(d, s, Af, 11, t); __syncthreads();

  // ---- epilogue: state[dd] = val[pi(dd)]; out = |state|/64 (verified R3) ----
  typedef _Float16 v4h __attribute__((ext_vector_type(4)));
  float* ob = out + (size_t)b * DIM;
  {
    const int g = t ^ (t >> 1);
    const int re_row = (g & 15) * 16 + ((g >> 4) & 15);
    const int ro = re_row ^ 8;   // odd-j rows: G1' ^= 8 (row low nibble)
    const int offA = (t & 1) ? 24 : 0;
    const int offB = (t & 1) ? 16 : 8;
    const v4h E0 = *(const v4h*)(s + adr(re_row, offA));
    const v4h E1 = *(const v4h*)(s + adr(re_row, offB));
    const v4h E2 = *(const v4h*)(s + adr(re_row, offA ^ 24));
    const v4h E3 = *(const v4h*)(s + adr(re_row, offB ^ 24));
    const v4h O0 = *(const v4h*)(s + adr(ro, offA));
    const v4h O1 = *(const v4h*)(s + adr(ro, offB));
    const v4h O2 = *(const v4h*)(s + adr(ro, offA ^ 24));
    const v4h O3 = *(const v4h*)(s + adr(ro, offB ^ 24));
    const v4h IE0 = *(const v4h*)(s + adr(re_row, 32 + offA));
    const v4h IE1 = *(const v4h*)(s + adr(re_row, 32 + offB));
    const v4h IE2 = *(const v4h*)(s + adr(re_row, 32 + (offA ^ 24)));
    const v4h IE3 = *(const v4h*)(s + adr(re_row, 32 + (offB ^ 24)));
    const v4h IO0 = *(const v4h*)(s + adr(ro, 32 + offA));
    const v4h IO1 = *(const v4h*)(s + adr(ro, 32 + offB));
    const v4h IO2 = *(const v4h*)(s + adr(ro, 32 + (offA ^ 24)));
    const v4h IO3 = *(const v4h*)(s + adr(ro, 32 + (offB ^ 24)));
#define MAG(J, VR, VI, IDX)                                                       \
  {                                                                               \
    const float re_ = (float)VR[IDX], im_ = (float)VI[IDX];                       \
    ob[((J) << 8) | t] = __builtin_amdgcn_sqrtf(re_ * re_ + im_ * im_) * 0.015625f; \
  }
    MAG(0, E0, IE0, 0)  MAG(2, E0, IE0, 3)  MAG(4, E1, IE1, 2)  MAG(6, E1, IE1, 1)
    MAG(8, E2, IE2, 0)  MAG(10, E2, IE2, 3) MAG(12, E3, IE3, 2) MAG(14, E3, IE3, 1)
    MAG(1, O0, IO0, 1)  MAG(3, O0, IO0, 2)  MAG(5, O1, IO1, 3)  MAG(7, O1, IO1, 0)
    MAG(9, O2, IO2, 1)  MAG(11, O2, IO2, 2) MAG(13, O3, IO3, 3) MAG(15, O3, IO3, 0)
#undef MAG
  }
}

extern "C" void kernel_launch(void* const* d_in, const int* in_sizes, int n_in,
                              void* d_out, int out_size, void* d_ws, size_t ws_size,
                              hipStream_t stream) {
  const float* x = (const float*)d_in[0];
  const float* ax = (const float*)d_in[1];
  const float* ay = (const float*)d_in[2];
  const float* az = (const float*)d_in[3];
  _Float16* Aw = (_Float16*)d_ws;  // 12 mats * 2 comps * 64 lanes * 8 halves = 24576 B
  make_gates2<<<1, 768, 0, stream>>>(ax, ay, az, Aw);
  qsim6<<<4096, 256, 0, stream>>>(x, (const v8h*)Aw, (float*)d_out);
}